// Round 18
// baseline (159.503 us; speedup 1.0000x reference)
//
#include <hip/hip_runtime.h>
#include <hip/hip_bf16.h>
#include <stdint.h>

typedef __attribute__((ext_vector_type(8))) short short8;
typedef __attribute__((ext_vector_type(4))) float f32x4;
typedef __attribute__((ext_vector_type(16))) float f32x16;
typedef __attribute__((ext_vector_type(4))) unsigned short us4;

#define B_ 4
#define N_ 2048
#define C_ 1024
#define H_ 16
#define D_ 64

__device__ __forceinline__ unsigned short f2bf(float f) {
  union { float f; unsigned u; } v; v.f = f;
  unsigned u = v.u;
  u += 0x7fffu + ((u >> 16) & 1u);
  return (unsigned short)(u >> 16);
}

// compiler-visible bf16 convert (RNE) — compiler fuses pairs into cvt_pk
__device__ __forceinline__ unsigned short bfc(float f) {
  union { __hip_bfloat16 h; unsigned short u; } v;
  v.h = __float2bfloat16(f);
  return v.u;
}

// pack two f32 -> one dword of 2 bf16 (lo first)
__device__ __forceinline__ unsigned pk2(float lo, float hi) {
  return ((unsigned)bfc(hi) << 16) | (unsigned)bfc(lo);
}

// v_permlane32_swap_b32: a.hi-lanes <-> b.lo-lanes (register-only, no memory)
__device__ __forceinline__ void pswap(unsigned& a, unsigned& b) {
  asm("v_permlane32_swap_b32 %0, %1" : "+v"(a), "+v"(b));
}

__device__ __forceinline__ void glds16(const unsigned short* g, const unsigned short* l) {
  __builtin_amdgcn_global_load_lds(
      (const __attribute__((address_space(1))) void*)(uintptr_t)g,
      (__attribute__((address_space(3))) void*)(uintptr_t)l, 16, 0, 0);
}

__device__ __forceinline__ f32x4 mfma16(short8 a, short8 b, f32x4 c) {
  return __builtin_amdgcn_mfma_f32_16x16x32_bf16(a, b, c, 0, 0, 0);
}

__device__ __forceinline__ f32x16 mfma32(short8 a, short8 b, f32x16 c) {
  return __builtin_amdgcn_mfma_f32_32x32x16_bf16(a, b, c, 0, 0, 0);
}

// ------- prep (rows 0..8191): x->bf16 + rstd; weight cast (blocks 8192+) ---
__global__ __launch_bounds__(256) void prep_cast_k(const float* __restrict__ x,
                                                   const float* __restrict__ gamma,
                                                   unsigned short* __restrict__ xb,
                                                   float* __restrict__ rstd_v,
                                                   const float* __restrict__ wq,
                                                   const float* __restrict__ wkv,
                                                   const float* __restrict__ wo,
                                                   unsigned short* __restrict__ dq,
                                                   unsigned short* __restrict__ dkv,
                                                   unsigned short* __restrict__ dwo) {
  const int t = threadIdx.x;
  if (blockIdx.x >= 8192) {  // weight cast: 2176 blocks x 256 float4
    const int i = (blockIdx.x - 8192) * 256 + t;
    if (i < 262144) {  // Wq * gamma[col]
      const float4 v = ((const float4*)wq)[i];
      const float4 gv = ((const float4*)gamma)[i & 255];
      us4 o;
      o.x = f2bf(v.x * gv.x); o.y = f2bf(v.y * gv.y);
      o.z = f2bf(v.z * gv.z); o.w = f2bf(v.w * gv.w);
      ((us4*)dq)[i] = o;
    } else {
      const float* s;
      unsigned short* d;
      int j;
      if (i < 294912) { s = wkv; d = dkv; j = i - 262144; }
      else { s = wo; d = dwo; j = i - 294912; }
      const float4 v = ((const float4*)s)[j];
      us4 o; o.x = f2bf(v.x); o.y = f2bf(v.y); o.z = f2bf(v.z); o.w = f2bf(v.w);
      ((us4*)d)[j] = o;
    }
    return;
  }
  const int row = blockIdx.x;
  const float4 v = ((const float4*)(x + (size_t)row * C_))[t];
  float s1 = v.x + v.y + v.z + v.w;
  float s2 = v.x * v.x + v.y * v.y + v.z * v.z + v.w * v.w;
#pragma unroll
  for (int off = 32; off > 0; off >>= 1) {
    s1 += __shfl_down(s1, off);
    s2 += __shfl_down(s2, off);
  }
  __shared__ float r1[4], r2[4];
  if ((t & 63) == 0) { r1[t >> 6] = s1; r2[t >> 6] = s2; }
  __syncthreads();
  s1 = r1[0] + r1[1] + r1[2] + r1[3];
  s2 = r2[0] + r2[1] + r2[2] + r2[3];
  const float var = (s2 - s1 * s1 * (1.0f / C_)) * (1.0f / (C_ - 1));
  const float rstd = 1.0f / (sqrtf(var) + 1e-7f);
  if (t == 0) rstd_v[row] = rstd;
  us4 a;
  a.x = f2bf(v.x); a.y = f2bf(v.y); a.z = f2bf(v.z); a.w = f2bf(v.w);
  ((us4*)(xb + (size_t)row * C_))[t] = a;
}

// ---------------- merged Q + KV GEMM: grid (9, 64), A = xb for all ----------
__global__ __launch_bounds__(256, 2) void qkv_gemm(const unsigned short* __restrict__ xb,
                                                   const unsigned short* __restrict__ wq,
                                                   const unsigned short* __restrict__ wkv,
                                                   const float* __restrict__ rstd_v,
                                                   unsigned short* __restrict__ qo,
                                                   unsigned short* __restrict__ kvo,
                                                   unsigned short* __restrict__ vtb) {
  const bool iskv = (blockIdx.x == 8);
  const unsigned short* Bw = iskv ? wkv : wq;
  const int n0 = iskv ? 0 : blockIdx.x * 128;
  const int K = 1024, m0 = blockIdx.y * 128;

  __shared__ unsigned short At[128 * 32];
  __shared__ unsigned short Bt[128 * 32];
  const int t = threadIdx.x;
  const int w = t >> 6, l = t & 63;
  const int ql = l & 15, g = l >> 4;
  const int wr = (w >> 1) * 64, wc = (w & 1) * 64;

  const int pr0 = t >> 2, pb0 = t & 3;
  const int lb0 = pb0 ^ ((pr0 >> 1) & 3);
  const int pr1 = 64 + (t >> 2);
  const int lb1 = pb0 ^ ((pr1 >> 1) & 3);
  const unsigned short* Ab = xb + (size_t)m0 * K;
  const unsigned short* Bb = Bw + (size_t)n0 * K;

  f32x4 acc[4][4];
#pragma unroll
  for (int i = 0; i < 4; ++i)
#pragma unroll
    for (int j = 0; j < 4; ++j) acc[i][j] = f32x4{0.f, 0.f, 0.f, 0.f};

  for (int k0 = 0; k0 < K; k0 += 32) {
    glds16(Ab + (size_t)pr0 * K + k0 + lb0 * 8, &At[w * 512]);
    glds16(Ab + (size_t)pr1 * K + k0 + lb1 * 8, &At[2048 + w * 512]);
    glds16(Bb + (size_t)pr0 * K + k0 + lb0 * 8, &Bt[w * 512]);
    glds16(Bb + (size_t)pr1 * K + k0 + lb1 * 8, &Bt[2048 + w * 512]);
    __syncthreads();
    short8 af[4], bfr[4];
#pragma unroll
    for (int i = 0; i < 4; ++i) {
      const int row = wr + i * 16 + ql;
      af[i] = *(const short8*)&At[row * 32 + ((g ^ ((row >> 1) & 3)) * 8)];
    }
#pragma unroll
    for (int i = 0; i < 4; ++i) {
      const int row = wc + i * 16 + ql;
      bfr[i] = *(const short8*)&Bt[row * 32 + ((g ^ ((row >> 1) & 3)) * 8)];
    }
#pragma unroll
    for (int mi = 0; mi < 4; ++mi)
#pragma unroll
      for (int ni = 0; ni < 4; ++ni)
        acc[mi][ni] = mfma16(af[mi], bfr[ni], acc[mi][ni]);
    __syncthreads();
  }

  if (!iskv) {  // Q: per-row scale rstd[row] * 0.125*log2(e)
    float rs[4][4];
#pragma unroll
    for (int mi = 0; mi < 4; ++mi)
#pragma unroll
      for (int r = 0; r < 4; ++r)
        rs[mi][r] = 0.18033688011112042f * rstd_v[m0 + wr + mi * 16 + g * 4 + r];
#pragma unroll
    for (int mi = 0; mi < 4; ++mi)
#pragma unroll
      for (int ni = 0; ni < 4; ++ni) {
        const int col = n0 + wc + ni * 16 + ql;
#pragma unroll
        for (int r = 0; r < 4; ++r) {
          const int row = m0 + wr + mi * 16 + g * 4 + r;
          qo[(size_t)row * 1024 + col] = f2bf(acc[mi][ni][r] * rs[mi][r]);
        }
      }
  } else if (wc == 0) {  // K half -> kvb[n][128], cols 0..63
#pragma unroll
    for (int mi = 0; mi < 4; ++mi)
#pragma unroll
      for (int ni = 0; ni < 4; ++ni) {
        const int col = ni * 16 + ql;
#pragma unroll
        for (int r = 0; r < 4; ++r) {
          const int row = m0 + wr + mi * 16 + g * 4 + r;
          kvo[(size_t)row * 128 + col] = f2bf(acc[mi][ni][r]);
        }
      }
  } else {  // V half -> vtb[b][d][n], PLAIN layout (32x32 attn reads b128)
    const int brow = m0 >> 11;  // batch index (2048 rows per batch)
    unsigned short* vb = vtb + (size_t)brow * 64 * 2048;
#pragma unroll
    for (int mi = 0; mi < 4; ++mi) {
      const int nbase = (m0 & 2047) + wr + mi * 16 + g * 4;
#pragma unroll
      for (int ni = 0; ni < 4; ++ni) {
        const int d = ni * 16 + ql;
        us4 st;
        st.x = f2bf(acc[mi][ni][0]);
        st.y = f2bf(acc[mi][ni][1]);
        st.z = f2bf(acc[mi][ni][2]);
        st.w = f2bf(acc[mi][ni][3]);
        *(us4*)&vb[(size_t)d * 2048 + nbase] = st;
      }
    }
  }
}

// ---------------- O GEMM: out[M,N] = A[M,K] * Bw[N,K]^T, *colscale, fp32 ----
__global__ __launch_bounds__(256, 2) void gemm_o(const unsigned short* __restrict__ A,
                                                 const unsigned short* __restrict__ Bw,
                                                 float* __restrict__ Cout,
                                                 const float* __restrict__ colscale,
                                                 int M, int N, int K) {
  __shared__ unsigned short At[128 * 32];
  __shared__ unsigned short Bt[128 * 32];
  const int t = threadIdx.x;
  const int w = t >> 6, l = t & 63;
  const int ql = l & 15, g = l >> 4;
  const int wr = (w >> 1) * 64, wc = (w & 1) * 64;
  const int m0 = blockIdx.y * 128, n0 = blockIdx.x * 128;

  const int pr0 = t >> 2, pb0 = t & 3;
  const int lb0 = pb0 ^ ((pr0 >> 1) & 3);
  const int pr1 = 64 + (t >> 2);
  const int lb1 = pb0 ^ ((pr1 >> 1) & 3);
  const unsigned short* Ab = A + (size_t)m0 * K;
  const unsigned short* Bb = Bw + (size_t)n0 * K;

  f32x4 acc[4][4];
#pragma unroll
  for (int i = 0; i < 4; ++i)
#pragma unroll
    for (int j = 0; j < 4; ++j) acc[i][j] = f32x4{0.f, 0.f, 0.f, 0.f};

  for (int k0 = 0; k0 < K; k0 += 32) {
    glds16(Ab + (size_t)pr0 * K + k0 + lb0 * 8, &At[w * 512]);
    glds16(Ab + (size_t)pr1 * K + k0 + lb1 * 8, &At[2048 + w * 512]);
    glds16(Bb + (size_t)pr0 * K + k0 + lb0 * 8, &Bt[w * 512]);
    glds16(Bb + (size_t)pr1 * K + k0 + lb1 * 8, &Bt[2048 + w * 512]);
    __syncthreads();
    short8 af[4], bfr[4];
#pragma unroll
    for (int i = 0; i < 4; ++i) {
      const int row = wr + i * 16 + ql;
      af[i] = *(const short8*)&At[row * 32 + ((g ^ ((row >> 1) & 3)) * 8)];
    }
#pragma unroll
    for (int i = 0; i < 4; ++i) {
      const int row = wc + i * 16 + ql;
      bfr[i] = *(const short8*)&Bt[row * 32 + ((g ^ ((row >> 1) & 3)) * 8)];
    }
#pragma unroll
    for (int mi = 0; mi < 4; ++mi)
#pragma unroll
      for (int ni = 0; ni < 4; ++ni)
        acc[mi][ni] = mfma16(af[mi], bfr[ni], acc[mi][ni]);
    __syncthreads();
  }

#pragma unroll
  for (int mi = 0; mi < 4; ++mi)
#pragma unroll
    for (int ni = 0; ni < 4; ++ni) {
      const int col = n0 + wc + ni * 16 + ql;
      const float cs = colscale[col];
#pragma unroll
      for (int r = 0; r < 4; ++r) {
        const int row = m0 + wr + mi * 16 + g * 4 + r;
        Cout[(size_t)row * N + col] = acc[mi][ni][r] * cs;
      }
    }
}

// ------- flash attention (MQA), 8 waves x 32 q (256 q/block), 32x32 MFMA ----
// r16's per-wave 32x32 pipeline (proven bit-exact) at r14's 8-wave occupancy:
// 512 threads, each wave owns 32 q; wave w stages K-rows/V^T-rows 8w+sr with
// the r14-proven one-issue-per-wave pattern (same XOR key, same invariant).
// Grid 512 = 2 blocks/CU x 8 waves -> 16 waves/CU potential (r16 measured 8).
// Per-q arithmetic identical to r16: max-free exp2 softmax, permlane P
// hand-off, plain vtb. launch_bounds(512,4): cap 128 VGPR, usage ~80.
__global__ __launch_bounds__(512, 4) void attn_k(const unsigned short* __restrict__ qb,
                                                 const unsigned short* __restrict__ kvb,
                                                 const unsigned short* __restrict__ vtb,
                                                 unsigned short* __restrict__ ao) {
  __shared__ unsigned short Kt[2][64 * 64];
  __shared__ unsigned short Vt[2][64 * 64];

  const int idx = blockIdx.x;  // 512 blocks: qc(8) x hd(16) x b(4)
  const int qc = idx & 7, hd = (idx >> 3) & 15, b = idx >> 7;
  const int t = threadIdx.x, w = t >> 6, l = t & 63;
  const int l31 = l & 31, hi = l >> 5, sw = l & 7;
  const int q0 = qc * 256 + w * 32;

  // Q fragments: B-operand (col=q=lane&31, k=8*hi+j), k-base 16*ks
  const unsigned short* qrow = qb + (size_t)(b * N_ + q0 + l31) * C_ + hd * D_;
  short8 Qf[4];
#pragma unroll
  for (int ks = 0; ks < 4; ++ks)
    Qf[ks] = *(const short8*)(qrow + 16 * ks + 8 * hi);

  const unsigned short* kvrow = kvb + (size_t)(b * N_) * 128;
  const unsigned short* vtrow = vtb + (size_t)b * 64 * 2048;
  const int sr = l >> 3;
  const int blk = ((l & 7) ^ sr) << 3;
  const int row0 = 8 * w + sr;  // 8 waves x 8 rows = 64 rows (r14 pattern)

  auto stage = [&](int bi, int kt) {
    glds16(kvrow + (size_t)(kt * 64 + row0) * 128 + blk, &Kt[bi][w * 512]);
    glds16(vtrow + (size_t)row0 * 2048 + kt * 64 + blk, &Vt[bi][w * 512]);
  };

  f32x16 o[2];
#pragma unroll
  for (int dh = 0; dh < 2; ++dh)
#pragma unroll
    for (int r = 0; r < 16; ++r) o[dh][r] = 0.f;
  float lsum = 0.f;

  auto tilec = [&](int bi) {
    short8 Pf[4];
#pragma unroll
    for (int half = 0; half < 2; ++half) {
      // K fragments: A-operand (row=kv=32*half+l31, k=8*hi+j), k-base 16*ks
      const int kro = (32 * half + l31) * 64;
      short8 Kf[4];
#pragma unroll
      for (int ks = 0; ks < 4; ++ks)
        Kf[ks] = *(const short8*)&Kt[bi][kro + (((2 * ks + hi) ^ sw) << 3)];
      f32x16 s;
#pragma unroll
      for (int r = 0; r < 16; ++r) s[r] = 0.f;
#pragma unroll
      for (int ks = 0; ks < 4; ++ks) s = mfma32(Kf[ks], Qf[ks], s);
      // max-free softmax + pack + permlane swap into PV B-operands
#pragma unroll
      for (int w2 = 0; w2 < 2; ++w2) {
        const float p0 = __builtin_amdgcn_exp2f(s[8 * w2 + 0]);
        const float p1 = __builtin_amdgcn_exp2f(s[8 * w2 + 1]);
        const float p2 = __builtin_amdgcn_exp2f(s[8 * w2 + 2]);
        const float p3 = __builtin_amdgcn_exp2f(s[8 * w2 + 3]);
        const float p4 = __builtin_amdgcn_exp2f(s[8 * w2 + 4]);
        const float p5 = __builtin_amdgcn_exp2f(s[8 * w2 + 5]);
        const float p6 = __builtin_amdgcn_exp2f(s[8 * w2 + 6]);
        const float p7 = __builtin_amdgcn_exp2f(s[8 * w2 + 7]);
        lsum += ((p0 + p1) + (p2 + p3)) + ((p4 + p5) + (p6 + p7));
        unsigned a0 = pk2(p0, p1), a1 = pk2(p2, p3);
        unsigned b0 = pk2(p4, p5), b1 = pk2(p6, p7);
        pswap(a0, b0);  // lanes<32 keep regs 0..3-pack; >=32 get partner's 4..7
        pswap(a1, b1);
        union { unsigned u[4]; short8 v; } cv;
        cv.u[0] = a0; cv.u[1] = a1; cv.u[2] = b0; cv.u[3] = b1;
        Pf[2 * half + w2] = cv.v;
      }
    }

    // PV: o^T[d][q] += V^T-frag (A: row=d, k=kv) x P-frag (B), 32x32x16
    __builtin_amdgcn_s_setprio(1);
#pragma unroll
    for (int dh = 0; dh < 2; ++dh) {
      const int vro = (32 * dh + l31) * 64;
      short8 Vf[4];
#pragma unroll
      for (int win = 0; win < 4; ++win)
        Vf[win] = *(const short8*)&Vt[bi][vro + (((2 * win + hi) ^ sw) << 3)];
#pragma unroll
      for (int win = 0; win < 4; ++win)
        o[dh] = mfma32(Vf[win], Pf[win], o[dh]);
    }
    __builtin_amdgcn_s_setprio(0);
  };

  stage(0, 0);
  for (int kt = 0; kt < 32; kt += 2) {
    __syncthreads();          // buf0 staged; prev buf1 reads done
    stage(1, kt + 1);         // prefetch, drained at next barrier
    tilec(0);
    __syncthreads();          // buf1 staged; buf0 reads done
    if (kt + 2 < 32) stage(0, kt + 2);
    tilec(1);
  }

  // lanes l and l+32 hold the same q with complementary kv partial sums
  lsum += __shfl_xor(lsum, 32);
  const float inv = 1.0f / lsum;

  // o layout: col=q=l31, d = 32*dh + (reg&3) + 8*(reg>>2) + 4*hi
  unsigned short* orow = ao + (size_t)(b * N_ + q0 + l31) * C_ + hd * D_;
#pragma unroll
  for (int dh = 0; dh < 2; ++dh)
#pragma unroll
    for (int r2 = 0; r2 < 4; ++r2) {
      us4 st;
      st.x = bfc(o[dh][4 * r2 + 0] * inv);
      st.y = bfc(o[dh][4 * r2 + 1] * inv);
      st.z = bfc(o[dh][4 * r2 + 2] * inv);
      st.w = bfc(o[dh][4 * r2 + 3] * inv);
      *(us4*)(orow + 32 * dh + 8 * r2 + 4 * hi) = st;
    }
}

extern "C" void kernel_launch(void* const* d_in, const int* in_sizes, int n_in,
                              void* d_out, int out_size, void* d_ws, size_t ws_size,
                              hipStream_t stream) {
  const float* x = (const float*)d_in[0];
  const float* gamma = (const float*)d_in[1];
  const float* Wq = (const float*)d_in[2];
  const float* Wkv = (const float*)d_in[3];
  const float* Wo = (const float*)d_in[4];
  const float* ls = (const float*)d_in[5];
  float* out = (float*)d_out;

  unsigned short* ws = (unsigned short*)d_ws;
  const size_t R = (size_t)B_ * N_;  // 8192 rows
  unsigned short* xb = ws;                        // R*C
  unsigned short* qbuf = xb + R * C_;             // R*C
  unsigned short* kvb = qbuf + R * C_;            // R*128 (K half used)
  unsigned short* aob = kvb + R * 128;            // R*C
  unsigned short* wqb = aob + R * C_;             // C*C (gamma-folded)
  unsigned short* wkvb = wqb + (size_t)C_ * C_;   // 128*C
  unsigned short* wob = wkvb + (size_t)128 * C_;  // C*C
  unsigned short* vtb = wob + (size_t)C_ * C_;    // 4*64*2048 (1 MB)
  float* rstd = (float*)(vtb + (size_t)4 * 64 * 2048);  // 8192 floats

  // prep (blocks 0..8191: xb + rstd) + weight casts (blocks 8192..10367)
  prep_cast_k<<<(int)R + 2176, 256, 0, stream>>>(x, gamma, xb, rstd,
                                                 Wq, Wkv, Wo, wqb, wkvb, wob);
  // q = rstd*scale*(xb @ (Wq*gamma)^T) ++ kv: K->kvb, V^T->vtb (plain)
  qkv_gemm<<<dim3(9, R / 128), 256, 0, stream>>>(xb, wqb, wkvb, rstd,
                                                 qbuf, kvb, vtb);
  attn_k<<<B_ * H_ * (N_ / 256), 512, 0, stream>>>(qbuf, kvb, vtb, aob);
  // out = (ao @ Wo^T) * ls_scale[col], fp32
  gemm_o<<<dim3(C_ / 128, R / 128), 256, 0, stream>>>(aob, wob, out, ls,
                                                      (int)R, C_, C_);
}